// Round 10
// baseline (637.171 us; speedup 1.0000x reference)
//
#include <hip/hip_runtime.h>
#include <hip/hip_bf16.h>

// WMSA round 6: swapped-operand QK^T -> wave-private softmax/P/O.
//  - St = mfma(K,Q): each lane owns one query row -> in-lane softmax,
//    only 2 shuffles per reduce, P in per-wave LDS strip (no barrier)
//  - window stage, P, O-stack, out-proj all wave-private -> 5 barriers total
//  - B-fragments register double-buffered from L2-resident bf16 weights
// One block (256 thr = 4 waves) per window; wave wv owns rows [16wv,16wv+16).

#define CH    96
#define MMTOK 49
#define HWD   224
#define PLANE (HWD * HWD)

typedef __attribute__((ext_vector_type(8))) __bf16 bfrag;
typedef __attribute__((ext_vector_type(4))) float  f4;
#define MFMA(a,b,c) __builtin_amdgcn_mfma_f32_16x16x32_bf16(a,b,c,0,0,0)

// ws layout (bf16 element offsets): qkv_w [288][96], out_w [96][96]
#define WS_OW  27648
#define WS_TOT 36864

// LDS pitches (bf16 elems); all row strides 16B-multiples for ds_read_b128
#define PW_S 104   // per-wave stack strip [16][96] (input, then O)
#define PW_K 40    // s_k [64][32]
#define PW_Q 40    // per-wave q strip [16][32]
#define PW_V 72    // s_vT [32][64]
#define PW_P 72    // per-wave P strip [16][64]

extern "C" __global__ void __launch_bounds__(256)
cvt_weights(const float* __restrict__ qw, const float* __restrict__ ow,
            __hip_bfloat16* __restrict__ ws)
{
    int i = blockIdx.x * 256 + threadIdx.x;
    if (i >= WS_TOT) return;
    ws[i] = __float2bfloat16(i < WS_OW ? qw[i] : ow[i - WS_OW]);
}

extern "C" __global__ void __launch_bounds__(256, 4)
wmsa_mfma(const float* __restrict__ x,
          const __hip_bfloat16* __restrict__ ws,
          const float* __restrict__ qkvb,   // f32 [288]
          const float* __restrict__ bt,     // f32 [507]
          const float* __restrict__ outb,   // f32 [96]
          float* __restrict__ out)
{
    __shared__ __align__(16) __hip_bfloat16 s_win[4][16 * PW_S]; // per-wave in/stack
    __shared__ __align__(16) __hip_bfloat16 s_k  [64 * PW_K];    // K [tok][d]
    __shared__ __align__(16) __hip_bfloat16 s_vT [32 * PW_V];    // V^T [d][tok]
    __shared__ __align__(16) __hip_bfloat16 s_q  [4][16 * PW_Q]; // per-wave Q strip
    __shared__ __align__(16) __hip_bfloat16 s_P  [4][16 * PW_P]; // per-wave P strip
    __shared__ float s_bias[507];

    const int tid  = threadIdx.x;
    // XCD-bijective swizzle (gridDim.x = 16384, %8==0)
    const int cpx  = gridDim.x >> 3;
    const int wid  = (blockIdx.x & 7) * cpx + (blockIdx.x >> 3);
    const int b    = wid >> 10;
    const int w    = wid & 1023;
    const int h0   = (w >> 5) * 7;
    const int w0   = (w & 31) * 7;
    const int lane = tid & 63;
    const int wv   = tid >> 6;
    const int lr   = lane & 15;
    const int lg   = lane >> 4;
    const int trow = wv * 16 + lg * 4;      // C-tile row base (global token)

    const __hip_bfloat16* QW = ws;
    const __hip_bfloat16* OW = ws + WS_OW;

    // ---- stage bias table (read first at head-0 softmax, after barrier [B]) ----
    for (int i = tid; i < 507; i += 256) s_bias[i] = bt[i];

    // ---- wave-private window strip load: rows wv*16..+16, 24 batched loads ----
    {
        const int rrow = lane >> 2;                    // 0..15 row-local
        const int t    = wv * 16 + rrow;
        const int tt   = (t < MMTOK) ? t : 0;
        const int ti   = tt / 7, tj = tt - ti * 7;
        const float* xp = x + ((size_t)(b * CH + (lane & 3)) * PLANE)
                            + (size_t)(h0 + ti) * HWD + (w0 + tj);
        float rx[24];
        #pragma unroll
        for (int k = 0; k < 24; ++k)
            rx[k] = xp[(size_t)k * 4 * PLANE];         // c = (lane&3) + 4k
        const float zm = (t < MMTOK) ? 1.f : 0.f;
        #pragma unroll
        for (int k = 0; k < 24; ++k)
            s_win[wv][rrow * PW_S + (lane & 3) + 4 * k] = __float2bfloat16(rx[k] * zm);
    }
    // same-wave RAW: compiler inserts lgkmcnt before these reads
    bfrag aq[3];
    #pragma unroll
    for (int k = 0; k < 3; ++k)
        aq[k] = *(const bfrag*)&s_win[wv][lr * PW_S + k * 32 + lg * 8];

    // ---- per-lane bias indices: p = wv*16+lr fixed; k = m*16+lg*4+r ----
    const int p   = wv * 16 + lr;
    const bool pok = (p < MMTOK);
    const int pp  = pok ? p : 48;
    const int a1p = ((pp / 7) * 13 + (pp % 7)) * 3 + 252;
    int bidx[16];
    #pragma unroll
    for (int m = 0; m < 4; ++m)
        #pragma unroll
        for (int r = 0; r < 4; ++r) {
            int kt = m * 16 + lg * 4 + r;
            int kc = (kt < MMTOK) ? kt : 48;           // clamp keeps idx in-range
            bidx[m * 4 + r] = a1p - ((kc / 7) * 13 + (kc % 7)) * 3;
        }

    const float inv_scale = 0.0180421959f;             // sqrt(3)/96

    // ==== per-head: QKV chunk GEMM -> attention -> O strip ====
    for (int ob = 0; ob < 3; ++ob) {
        // --- GEMM chunk ob, register-double-buffered B-frags from L2 ---
        const __hip_bfloat16* QWrow = QW + (ob * 96 + lr) * 96 + lg * 8;
        f4 acc[6];
        #pragma unroll
        for (int n = 0; n < 6; ++n) {
            float bb = qkvb[ob * 96 + n * 16 + lr];
            acc[n] = f4{bb, bb, bb, bb};
        }
        bfrag b0[6], b1[6];
        #pragma unroll
        for (int n = 0; n < 6; ++n) b0[n] = *(const bfrag*)&QWrow[n * 16 * 96 + 0 * 32];
        #pragma unroll
        for (int n = 0; n < 6; ++n) b1[n] = *(const bfrag*)&QWrow[n * 16 * 96 + 1 * 32];
        __builtin_amdgcn_s_setprio(1);
        #pragma unroll
        for (int n = 0; n < 6; ++n) acc[n] = MFMA(aq[0], b0[n], acc[n]);
        __builtin_amdgcn_s_setprio(0);
        #pragma unroll
        for (int n = 0; n < 6; ++n) b0[n] = *(const bfrag*)&QWrow[n * 16 * 96 + 2 * 32];
        __builtin_amdgcn_s_setprio(1);
        #pragma unroll
        for (int n = 0; n < 6; ++n) acc[n] = MFMA(aq[1], b1[n], acc[n]);
        #pragma unroll
        for (int n = 0; n < 6; ++n) acc[n] = MFMA(aq[2], b0[n], acc[n]);
        __builtin_amdgcn_s_setprio(0);

        if (ob) __syncthreads();   // [A] all waves done reading prev head's s_k/s_vT

        // C-store: n=0,1 -> Q (wave-private) ; n=2,3 -> K ; n=4,5 -> V^T
        #pragma unroll
        for (int n = 0; n < 6; ++n) {
            int part = n >> 1;
            int d = ((n & 1) << 4) + lr;
            #pragma unroll
            for (int r = 0; r < 4; ++r) {
                __hip_bfloat16 hv = __float2bfloat16(acc[n][r]);
                if (part == 0)      s_q[wv][(lg * 4 + r) * PW_Q + d] = hv;
                else if (part == 1) s_k[(trow + r) * PW_K + d] = hv;
                else                s_vT[d * PW_V + (trow + r)] = hv;
            }
        }
        __syncthreads();           // [B] K, V visible to all waves

        // --- swapped QK^T: St[m] = mfma(K rows m*16+lr, Q rows wv*16+lr) ---
        // lane (lg,lr): St[k=m*16+lg*4+r][p=wv*16+lr] -> one query row per lane
        bfrag qf = *(const bfrag*)&s_q[wv][lr * PW_Q + lg * 8];
        f4 sc[4];
        __builtin_amdgcn_s_setprio(1);
        #pragma unroll
        for (int m = 0; m < 4; ++m) {
            bfrag kf = *(const bfrag*)&s_k[(m * 16 + lr) * PW_K + lg * 8];
            f4 z = f4{0.f, 0.f, 0.f, 0.f};
            sc[m] = MFMA(kf, qf, z);
        }
        __builtin_amdgcn_s_setprio(0);

        // --- in-lane softmax for query row p (16 scores per lane) ---
        float bv[16], val[16];
        #pragma unroll
        for (int i = 0; i < 16; ++i) bv[i] = s_bias[bidx[i] + ob];
        #pragma unroll
        for (int m = 0; m < 4; ++m)
            #pragma unroll
            for (int r = 0; r < 4; ++r)
                val[m * 4 + r] = fmaf(sc[m][r], inv_scale, bv[m * 4 + r]);
        // max over own 16 (garbage k>=49 entries included: harmless, exps zeroed)
        float mx01 = fmaxf(fmaxf(val[0], val[1]), fmaxf(val[2], val[3]));
        float mx23 = fmaxf(fmaxf(val[4], val[5]), fmaxf(val[6], val[7]));
        float mx45 = fmaxf(fmaxf(val[8], val[9]), fmaxf(val[10], val[11]));
        float mx67 = fmaxf(fmaxf(val[12], val[13]), fmaxf(val[14], val[15]));
        float mx = fmaxf(fmaxf(mx01, mx23), fmaxf(mx45, mx67));
        mx = fmaxf(mx, __shfl_xor(mx, 16));
        mx = fmaxf(mx, __shfl_xor(mx, 32));
        // exp, zero invalid keys, sum
        float sum = 0.f;
        #pragma unroll
        for (int m = 0; m < 4; ++m)
            #pragma unroll
            for (int r = 0; r < 4; ++r) {
                int i = m * 4 + r;
                float e = __expf(val[i] - mx);
                e = (m * 16 + lg * 4 + r < MMTOK) ? e : 0.f;
                val[i] = e;
                sum += e;
            }
        sum += __shfl_xor(sum, 16);
        sum += __shfl_xor(sum, 32);
        const float inv = pok ? (1.0f / sum) : 0.f;

        // P strip (wave-private): lane writes its 16 values, 4x uint2
        #pragma unroll
        for (int m = 0; m < 4; ++m) {
            union { __hip_bfloat16 h[4]; uint2 u; } pk;
            #pragma unroll
            for (int r = 0; r < 4; ++r) pk.h[r] = __float2bfloat16(val[m * 4 + r] * inv);
            *(uint2*)&s_P[wv][lr * PW_P + m * 16 + lg * 4] = pk.u;
        }
        // same-wave RAW on s_P: lgkmcnt ordering, no barrier

        // --- PV: O strip [16 p][32 d] = P[16][64] x V[64][32] ---
        bfrag pa[2];
        #pragma unroll
        for (int kb2 = 0; kb2 < 2; ++kb2)
            pa[kb2] = *(const bfrag*)&s_P[wv][lr * PW_P + kb2 * 32 + lg * 8];
        __builtin_amdgcn_s_setprio(1);
        #pragma unroll
        for (int n = 0; n < 2; ++n) {
            f4 oc = f4{0.f, 0.f, 0.f, 0.f};
            #pragma unroll
            for (int kb2 = 0; kb2 < 2; ++kb2) {
                bfrag vb = *(const bfrag*)&s_vT[(n * 16 + lr) * PW_V + kb2 * 32 + lg * 8];
                oc = MFMA(pa[kb2], vb, oc);
            }
            #pragma unroll
            for (int r = 0; r < 4; ++r)
                s_win[wv][(lg * 4 + r) * PW_S + ob * 32 + n * 16 + lr] = __float2bfloat16(oc[r]);
        }
        __builtin_amdgcn_s_setprio(0);
        // no barrier: next head's [A]/[B] protect s_k/s_vT; s_win is wave-private
    }

    // ==== output projection (all wave-private + global B) ====
    bfrag sa[3];
    #pragma unroll
    for (int k = 0; k < 3; ++k)
        sa[k] = *(const bfrag*)&s_win[wv][lr * PW_S + k * 32 + lg * 8];
    f4 yac[6];
    #pragma unroll
    for (int n = 0; n < 6; ++n) {
        float bb = outb[n * 16 + lr];
        yac[n] = f4{bb, bb, bb, bb};
    }
    {
        const __hip_bfloat16* OWrow = OW + lr * 96 + lg * 8;
        bfrag c0[6], c1[6];
        #pragma unroll
        for (int n = 0; n < 6; ++n) c0[n] = *(const bfrag*)&OWrow[n * 16 * 96 + 0 * 32];
        #pragma unroll
        for (int n = 0; n < 6; ++n) c1[n] = *(const bfrag*)&OWrow[n * 16 * 96 + 1 * 32];
        __builtin_amdgcn_s_setprio(1);
        #pragma unroll
        for (int n = 0; n < 6; ++n) yac[n] = MFMA(sa[0], c0[n], yac[n]);
        __builtin_amdgcn_s_setprio(0);
        #pragma unroll
        for (int n = 0; n < 6; ++n) c0[n] = *(const bfrag*)&OWrow[n * 16 * 96 + 2 * 32];
        __builtin_amdgcn_s_setprio(1);
        #pragma unroll
        for (int n = 0; n < 6; ++n) yac[n] = MFMA(sa[1], c1[n], yac[n]);
        #pragma unroll
        for (int n = 0; n < 6; ++n) yac[n] = MFMA(sa[2], c0[n], yac[n]);
        __builtin_amdgcn_s_setprio(0);
    }

    // store: flat = w*49 + t ; out[b][o][flat/224][flat%224]
    #pragma unroll
    for (int r = 0; r < 4; ++r) {
        int t = trow + r;
        if (t < MMTOK) {
            int flat = w * MMTOK + t;
            int ho = flat / HWD, wo = flat - ho * HWD;
            float* op = out + (size_t)(b * CH + lr) * PLANE + (size_t)ho * HWD + wo;
            #pragma unroll
            for (int n = 0; n < 6; ++n)
                op[(size_t)n * 16 * PLANE] = yac[n][r];
        }
    }
}

extern "C" void kernel_launch(void* const* d_in, const int* in_sizes, int n_in,
                              void* d_out, int out_size, void* d_ws, size_t ws_size,
                              hipStream_t stream) {
    const float* x  = (const float*)d_in[0];
    const float* qw = (const float*)d_in[1];
    const float* qb = (const float*)d_in[2];
    const float* bt = (const float*)d_in[3];
    const float* ow = (const float*)d_in[4];
    const float* ob = (const float*)d_in[5];
    float* out      = (float*)d_out;
    __hip_bfloat16* ws = (__hip_bfloat16*)d_ws;

    cvt_weights<<<(WS_TOT + 255) / 256, 256, 0, stream>>>(qw, ow, ws);

    int B = in_sizes[0] / (CH * HWD * HWD);      // 16
    int nblocks = B * 1024;                      // one block per window (16384, %8==0)
    wmsa_mfma<<<nblocks, 256, 0, stream>>>(x, ws, qb, bt, ob, out);
}

// Round 11
// 607.502 us; speedup vs baseline: 1.0488x; 1.0488x over previous
//
#include <hip/hip_runtime.h>
#include <hip/hip_bf16.h>

// WMSA round 7: round-10 structure (swapped QK^T, wave-private softmax, few barriers)
// with round-9 x-load pattern (uniform plane per instruction, block-wide s_win)
// and round-8 store form (confirmed WRITE == output size). 6 barriers total.
// One block (256 thr = 4 waves) per window; wave wv owns rows [16wv,16wv+16).

#define CH    96
#define MMTOK 49
#define HWD   224
#define PLANE (HWD * HWD)

typedef __attribute__((ext_vector_type(8))) __bf16 bfrag;
typedef __attribute__((ext_vector_type(4))) float  f4;
#define MFMA(a,b,c) __builtin_amdgcn_mfma_f32_16x16x32_bf16(a,b,c,0,0,0)

// ws layout (bf16 element offsets): qkv_w [288][96], out_w [96][96]
#define WS_OW  27648
#define WS_TOT 36864

// LDS pitches (bf16 elems); all row strides 16B-multiples for ds_read_b128
#define PW_S 104   // s_win [64][104]: input, then O-stack (wave-private rows)
#define PW_K 40    // s_k [64][32]
#define PW_Q 40    // per-wave q strip [16][32]
#define PW_V 72    // s_vT [32][64]
#define PW_P 72    // per-wave P strip [16][64]

extern "C" __global__ void __launch_bounds__(256)
cvt_weights(const float* __restrict__ qw, const float* __restrict__ ow,
            __hip_bfloat16* __restrict__ ws)
{
    int i = blockIdx.x * 256 + threadIdx.x;
    if (i >= WS_TOT) return;
    ws[i] = __float2bfloat16(i < WS_OW ? qw[i] : ow[i - WS_OW]);
}

extern "C" __global__ void __launch_bounds__(256, 4)
wmsa_mfma(const float* __restrict__ x,
          const __hip_bfloat16* __restrict__ ws,
          const float* __restrict__ qkvb,   // f32 [288]
          const float* __restrict__ bt,     // f32 [507]
          const float* __restrict__ outb,   // f32 [96]
          float* __restrict__ out)
{
    __shared__ __align__(16) __hip_bfloat16 s_win[64 * PW_S];    // block-wide in/stack
    __shared__ __align__(16) __hip_bfloat16 s_k  [64 * PW_K];    // K [tok][d]
    __shared__ __align__(16) __hip_bfloat16 s_vT [32 * PW_V];    // V^T [d][tok]
    __shared__ __align__(16) __hip_bfloat16 s_q  [4][16 * PW_Q]; // per-wave Q strip
    __shared__ __align__(16) __hip_bfloat16 s_P  [4][16 * PW_P]; // per-wave P strip
    __shared__ float s_bias[507];

    const int tid  = threadIdx.x;
    // XCD-bijective swizzle (gridDim.x = 16384, %8==0)
    const int cpx  = gridDim.x >> 3;
    const int wid  = (blockIdx.x & 7) * cpx + (blockIdx.x >> 3);
    const int b    = wid >> 10;
    const int w    = wid & 1023;
    const int h0   = (w >> 5) * 7;
    const int w0   = (w & 31) * 7;
    const int lane = tid & 63;
    const int wv   = tid >> 6;
    const int lr   = lane & 15;
    const int lg   = lane >> 4;
    const int trow = wv * 16 + lg * 4;      // C-tile row base (global token)

    const __hip_bfloat16* QW = ws;
    const __hip_bfloat16* OW = ws + WS_OW;

    // ---- stage bias table ----
    for (int i = tid; i < 507; i += 256) s_bias[i] = bt[i];

    // ---- window load (round-9 pattern): t = lane, c = wv + 4k (uniform plane
    //      per instruction), 24 batched loads, one drain ----
    {
        const int t  = lane;
        const int tt = (t < MMTOK) ? t : 0;           // clamped for safe address
        const int ti = tt / 7, tj = tt - ti * 7;
        const float* xp = x + ((size_t)(b * CH + wv) * PLANE)
                            + (size_t)(h0 + ti) * HWD + (w0 + tj);
        float rx[24];
        #pragma unroll
        for (int k = 0; k < 24; ++k)
            rx[k] = xp[(size_t)k * 4 * PLANE];        // c = wv + 4k
        const float zm = (t < MMTOK) ? 1.f : 0.f;
        #pragma unroll
        for (int k = 0; k < 24; ++k)
            s_win[t * PW_S + wv + 4 * k] = __float2bfloat16(rx[k] * zm);
    }
    __syncthreads();                                   // [1] s_win complete

    // A-fragments (rows wv*16+lr, K=96 = 3 kblocks)
    bfrag aq[3];
    #pragma unroll
    for (int k = 0; k < 3; ++k)
        aq[k] = *(const bfrag*)&s_win[(wv * 16 + lr) * PW_S + k * 32 + lg * 8];

    // ---- per-lane bias indices: p = wv*16+lr fixed; k = m*16+lg*4+r ----
    const int p   = wv * 16 + lr;
    const bool pok = (p < MMTOK);
    const int pp  = pok ? p : 48;
    const int a1p = ((pp / 7) * 13 + (pp % 7)) * 3 + 252;
    int bidx[16];
    #pragma unroll
    for (int m = 0; m < 4; ++m)
        #pragma unroll
        for (int r = 0; r < 4; ++r) {
            int kt = m * 16 + lg * 4 + r;
            int kc = (kt < MMTOK) ? kt : 48;           // clamp keeps idx in-range
            bidx[m * 4 + r] = a1p - ((kc / 7) * 13 + (kc % 7)) * 3;
        }

    const float inv_scale = 0.0180421959f;             // sqrt(3)/96

    // ==== per-head: QKV chunk GEMM -> attention -> O strip ====
    for (int ob = 0; ob < 3; ++ob) {
        // --- GEMM chunk ob, register-double-buffered B-frags from L2 ---
        const __hip_bfloat16* QWrow = QW + (ob * 96 + lr) * 96 + lg * 8;
        f4 acc[6];
        #pragma unroll
        for (int n = 0; n < 6; ++n) {
            float bb = qkvb[ob * 96 + n * 16 + lr];
            acc[n] = f4{bb, bb, bb, bb};
        }
        bfrag b0[6], b1[6];
        #pragma unroll
        for (int n = 0; n < 6; ++n) b0[n] = *(const bfrag*)&QWrow[n * 16 * 96 + 0 * 32];
        #pragma unroll
        for (int n = 0; n < 6; ++n) b1[n] = *(const bfrag*)&QWrow[n * 16 * 96 + 1 * 32];
        __builtin_amdgcn_s_setprio(1);
        #pragma unroll
        for (int n = 0; n < 6; ++n) acc[n] = MFMA(aq[0], b0[n], acc[n]);
        __builtin_amdgcn_s_setprio(0);
        #pragma unroll
        for (int n = 0; n < 6; ++n) b0[n] = *(const bfrag*)&QWrow[n * 16 * 96 + 2 * 32];
        __builtin_amdgcn_s_setprio(1);
        #pragma unroll
        for (int n = 0; n < 6; ++n) acc[n] = MFMA(aq[1], b1[n], acc[n]);
        #pragma unroll
        for (int n = 0; n < 6; ++n) acc[n] = MFMA(aq[2], b0[n], acc[n]);
        __builtin_amdgcn_s_setprio(0);

        if (ob) __syncthreads();   // [A] all waves done reading prev head's s_k/s_vT

        // C-store: n=0,1 -> Q (wave-private) ; n=2,3 -> K ; n=4,5 -> V^T
        #pragma unroll
        for (int n = 0; n < 6; ++n) {
            int part = n >> 1;
            int d = ((n & 1) << 4) + lr;
            #pragma unroll
            for (int r = 0; r < 4; ++r) {
                __hip_bfloat16 hv = __float2bfloat16(acc[n][r]);
                if (part == 0)      s_q[wv][(lg * 4 + r) * PW_Q + d] = hv;
                else if (part == 1) s_k[(trow + r) * PW_K + d] = hv;
                else                s_vT[d * PW_V + (trow + r)] = hv;
            }
        }
        __syncthreads();           // [B] K, V visible to all waves

        // --- swapped QK^T: St[m] = mfma(K rows m*16+lr, Q rows wv*16+lr) ---
        // lane (lg,lr): St[k=m*16+lg*4+r][p=wv*16+lr] -> one query row per lane
        bfrag qf = *(const bfrag*)&s_q[wv][lr * PW_Q + lg * 8];
        f4 sc[4];
        __builtin_amdgcn_s_setprio(1);
        #pragma unroll
        for (int m = 0; m < 4; ++m) {
            bfrag kf = *(const bfrag*)&s_k[(m * 16 + lr) * PW_K + lg * 8];
            f4 z = f4{0.f, 0.f, 0.f, 0.f};
            sc[m] = MFMA(kf, qf, z);
        }
        __builtin_amdgcn_s_setprio(0);

        // --- in-lane softmax for query row p (16 scores per lane) ---
        float bv[16], val[16];
        #pragma unroll
        for (int i = 0; i < 16; ++i) bv[i] = s_bias[bidx[i] + ob];
        #pragma unroll
        for (int m = 0; m < 4; ++m)
            #pragma unroll
            for (int r = 0; r < 4; ++r)
                val[m * 4 + r] = fmaf(sc[m][r], inv_scale, bv[m * 4 + r]);
        float mx01 = fmaxf(fmaxf(val[0], val[1]), fmaxf(val[2], val[3]));
        float mx23 = fmaxf(fmaxf(val[4], val[5]), fmaxf(val[6], val[7]));
        float mx45 = fmaxf(fmaxf(val[8], val[9]), fmaxf(val[10], val[11]));
        float mx67 = fmaxf(fmaxf(val[12], val[13]), fmaxf(val[14], val[15]));
        float mx = fmaxf(fmaxf(mx01, mx23), fmaxf(mx45, mx67));
        mx = fmaxf(mx, __shfl_xor(mx, 16));
        mx = fmaxf(mx, __shfl_xor(mx, 32));
        float sum = 0.f;
        #pragma unroll
        for (int m = 0; m < 4; ++m)
            #pragma unroll
            for (int r = 0; r < 4; ++r) {
                int i = m * 4 + r;
                float e = __expf(val[i] - mx);
                e = (m * 16 + lg * 4 + r < MMTOK) ? e : 0.f;
                val[i] = e;
                sum += e;
            }
        sum += __shfl_xor(sum, 16);
        sum += __shfl_xor(sum, 32);
        const float inv = pok ? (1.0f / sum) : 0.f;

        // P strip (wave-private): lane writes its 16 values, 4x uint2
        #pragma unroll
        for (int m = 0; m < 4; ++m) {
            union { __hip_bfloat16 h[4]; uint2 u; } pk;
            #pragma unroll
            for (int r = 0; r < 4; ++r) pk.h[r] = __float2bfloat16(val[m * 4 + r] * inv);
            *(uint2*)&s_P[wv][lr * PW_P + m * 16 + lg * 4] = pk.u;
        }
        // same-wave RAW on s_P: lgkmcnt ordering, no barrier

        // --- PV: O strip [16 p][32 d]; store into s_win rows (wave-private) ---
        bfrag pa[2];
        #pragma unroll
        for (int kb2 = 0; kb2 < 2; ++kb2)
            pa[kb2] = *(const bfrag*)&s_P[wv][lr * PW_P + kb2 * 32 + lg * 8];
        __builtin_amdgcn_s_setprio(1);
        #pragma unroll
        for (int n = 0; n < 2; ++n) {
            f4 oc = f4{0.f, 0.f, 0.f, 0.f};
            #pragma unroll
            for (int kb2 = 0; kb2 < 2; ++kb2) {
                bfrag vb = *(const bfrag*)&s_vT[(n * 16 + lr) * PW_V + kb2 * 32 + lg * 8];
                oc = MFMA(pa[kb2], vb, oc);
            }
            #pragma unroll
            for (int r = 0; r < 4; ++r)
                s_win[(trow + r) * PW_S + ob * 32 + n * 16 + lr] = __float2bfloat16(oc[r]);
        }
        __builtin_amdgcn_s_setprio(0);
        // no barrier: next head's [A]/[B] protect s_k/s_vT; rows are wave-private
    }

    // ==== output projection (A = own rows of s_win, B from global L2) ====
    bfrag sa[3];
    #pragma unroll
    for (int k = 0; k < 3; ++k)
        sa[k] = *(const bfrag*)&s_win[(wv * 16 + lr) * PW_S + k * 32 + lg * 8];
    f4 yac[6];
    #pragma unroll
    for (int n = 0; n < 6; ++n) {
        float bb = outb[n * 16 + lr];
        yac[n] = f4{bb, bb, bb, bb};
    }
    {
        const __hip_bfloat16* OWrow = OW + lr * 96 + lg * 8;
        bfrag c0[6], c1[6];
        #pragma unroll
        for (int n = 0; n < 6; ++n) c0[n] = *(const bfrag*)&OWrow[n * 16 * 96 + 0 * 32];
        #pragma unroll
        for (int n = 0; n < 6; ++n) c1[n] = *(const bfrag*)&OWrow[n * 16 * 96 + 1 * 32];
        __builtin_amdgcn_s_setprio(1);
        #pragma unroll
        for (int n = 0; n < 6; ++n) yac[n] = MFMA(sa[0], c0[n], yac[n]);
        __builtin_amdgcn_s_setprio(0);
        #pragma unroll
        for (int n = 0; n < 6; ++n) c0[n] = *(const bfrag*)&OWrow[n * 16 * 96 + 2 * 32];
        __builtin_amdgcn_s_setprio(1);
        #pragma unroll
        for (int n = 0; n < 6; ++n) yac[n] = MFMA(sa[1], c1[n], yac[n]);
        #pragma unroll
        for (int n = 0; n < 6; ++n) yac[n] = MFMA(sa[2], c0[n], yac[n]);
        __builtin_amdgcn_s_setprio(0);
    }

    // store (round-8 form, confirmed WRITE == output size):
    // flat = w*49 + t ; out[b][o][flat/224][flat%224]
    #pragma unroll
    for (int n = 0; n < 6; ++n) {
        int o = n * 16 + lr;
        #pragma unroll
        for (int r = 0; r < 4; ++r) {
            int t = trow + r;
            if (t < MMTOK) {
                int flat = w * MMTOK + t;
                int ho = flat / HWD, wo = flat - ho * HWD;
                out[((b * CH + o) * HWD + ho) * HWD + wo] = yac[n][r];
            }
        }
    }
}

extern "C" void kernel_launch(void* const* d_in, const int* in_sizes, int n_in,
                              void* d_out, int out_size, void* d_ws, size_t ws_size,
                              hipStream_t stream) {
    const float* x  = (const float*)d_in[0];
    const float* qw = (const float*)d_in[1];
    const float* qb = (const float*)d_in[2];
    const float* bt = (const float*)d_in[3];
    const float* ow = (const float*)d_in[4];
    const float* ob = (const float*)d_in[5];
    float* out      = (float*)d_out;
    __hip_bfloat16* ws = (__hip_bfloat16*)d_ws;

    cvt_weights<<<(WS_TOT + 255) / 256, 256, 0, stream>>>(qw, ow, ws);

    int B = in_sizes[0] / (CH * HWD * HWD);      // 16
    int nblocks = B * 1024;                      // one block per window (16384, %8==0)
    wmsa_mfma<<<nblocks, 256, 0, stream>>>(x, ws, qb, bt, ob, out);
}